// Round 26
// baseline (215.037 us; speedup 1.0000x reference)
//
#include <hip/hip_runtime.h>

#define BB 16
#define HH 256
#define WW 256
#define PC 258                 // padded cols/rows
#define PP ((size_t)(PC * PC)) // 66564 px per padded img

typedef int i32x4 __attribute__((ext_vector_type(4)));
typedef int i32x16 __attribute__((ext_vector_type(16)));
typedef float f32x16 __attribute__((ext_vector_type(16)));
typedef _Float16 f16x8 __attribute__((ext_vector_type(8)));

// ================= fused prep =================
__global__ __launch_bounds__(256) void prep_kernel(
    const float* __restrict__ x, const float* __restrict__ w1,
    const float* __restrict__ w2, const float* __restrict__ w3,
    const float* __restrict__ w4, const float* __restrict__ w5,
    const float* __restrict__ w6, const float* __restrict__ w7,
    const float* __restrict__ wfc,
    _Float16* __restrict__ pre, _Float16* __restrict__ frag1,
    signed char* __restrict__ wfr, int* __restrict__ wfcq,
    int* __restrict__ gmax, signed char* __restrict__ A0) {
  int bid = blockIdx.x, tid = threadIdx.x;
  if (bid < 4096) {
    int px = bid * 256 + tid;  // 1,048,576 interior pixels
    int b = px >> 16, rem = px & 65535;
    int y = rem >> 8, xc = rem & 255;
    const float* xp = x + (size_t)b * 4 * 65536 + rem;
    f16x8 o;
#pragma unroll
    for (int ic = 0; ic < 4; ++ic) {
      float v = xp[ic * 65536];
      _Float16 hf = (_Float16)v;
      float r = v - (float)hf;
      o[ic * 2] = hf;
      o[ic * 2 + 1] = (_Float16)r;
    }
    *(f16x8*)(pre + ((size_t)b * PP + (size_t)(y + 1) * PC + (xc + 1)) * 8) = o;
  } else if (bid < 4312) {
    int i = (bid - 4096) * 256 + tid;  // 6 x 9216
    int layer = i / 9216, within = i - layer * 9216;
    const float* w = layer == 0 ? w2 : layer == 1 ? w3 : layer == 2 ? w4
                   : layer == 3 ? w5 : layer == 4 ? w6 : w7;
    int t = within >> 10;
    int l = (within >> 4) & 63;
    int j = within & 15;
    int ic = (l >> 5) * 16 + j;
    int oc = l & 31;
    int q = (int)rintf(w[oc * 288 + ic * 9 + t] * 128.0f);
    q = min(127, max(-127, q));
    wfr[(size_t)layer * 9216 + within] = (signed char)q;
  } else if (bid == 4312) {
    for (int p = tid; p < 384; p += 256) {
      int s = p >> 6, l = p & 63;
      int dr = s >> 1, pp = s & 1;
      int oc = l & 31, half = l >> 5;
      int dx = pp * 2 + half;
#pragma unroll
      for (int j = 0; j < 8; ++j) {
        int ic = j >> 1;
        _Float16 v = (_Float16)0.f;
        if (!(pp == 1 && half == 1)) {
          int q = (int)rintf(w1[oc * 36 + ic * 9 + dr * 3 + dx] * 128.0f);
          q = min(127, max(-127, q));
          v = (_Float16)((float)q * 0.0078125f);  // exact in fp16
        }
        frag1[s * 512 + l * 8 + j] = v;
      }
    }
    if (tid < 32) {
      int q = (int)rintf(wfc[tid] * 128.0f);
      q = min(127, max(-127, q));
      wfcq[tid] = q;
    }
    for (int i2 = tid; i2 < 512; i2 += 256) gmax[i2] = -128;
  } else {
    int idx = (bid - 4313) * 256 + tid;  // 16*1028 = 16448 pad px
    if (idx < 16448) {
      int img = idx / 1028, p = idx - img * 1028;
      int row, col;
      if (p < 258) { row = 0; col = p; }
      else if (p < 516) { row = 257; col = p - 258; }
      else { int q2 = p - 516; row = 1 + (q2 & 255); col = (q2 >> 8) ? 257 : 0; }
      size_t off = (size_t)img * PP + (size_t)row * PC + col;
      f16x8 z16 = {};
      *(f16x8*)(pre + off * 8) = z16;
      i32x4 z = {};
      ((i32x4*)(A0 + off * 32))[0] = z;
      ((i32x4*)(A0 + off * 32 + 16))[0] = z;
    }
  }
}

// zero the pads of A1 (must run AFTER conv1 consumed pre, which aliases A1)
__global__ __launch_bounds__(256) void pad_kernel(signed char* __restrict__ A1) {
  int idx = blockIdx.x * 256 + threadIdx.x;
  if (idx < 16448) {
    int img = idx / 1028, p = idx - img * 1028;
    int row, col;
    if (p < 258) { row = 0; col = p; }
    else if (p < 516) { row = 257; col = p - 258; }
    else { int q2 = p - 516; row = 1 + (q2 & 255); col = (q2 >> 8) ? 257 : 0; }
    size_t off = (size_t)img * PP + (size_t)row * PC + col;
    i32x4 z = {};
    ((i32x4*)(A1 + off * 32))[0] = z;
    ((i32x4*)(A1 + off * 32 + 16))[0] = z;
  }
}

__device__ __forceinline__ int pack4(int q0, int q1, int q2, int q3) {
  return (q0 & 255) | ((q1 & 255) << 8) | ((q2 & 255) << 16) | ((q3 & 255) << 24);
}

// Exact integer RNE: rne(a/128) = (a + 63 + ((a>>7)&1)) >> 7, bit-identical.
__device__ __forceinline__ int quant1(int a) {
  int q = (a + 63 + ((a >> 7) & 1)) >> 7;
  return min(127, max(-127, q));
}

__device__ __forceinline__ int quant_max(const i32x16& acc, int mymax) {
#pragma unroll
  for (int r = 0; r < 16; ++r) mymax = max(mymax, quant1(acc[r]));
  return mymax;
}

__device__ __forceinline__ i32x4 half_swap(int v0, int v1, int v2, int v3, int hi) {
  int s0 = hi ? v0 : v2;
  int s1 = hi ? v1 : v3;
  int r0 = __shfl_xor(s0, 32);
  int r1 = __shfl_xor(s1, 32);
  i32x4 ch;
  ch.x = hi ? r0 : v0;
  ch.y = hi ? v2 : r0;
  ch.z = hi ? r1 : v1;
  ch.w = hi ? v3 : r1;
  return ch;
}

// ================= conv1: padded pre -> padded A0 ======
__global__ __launch_bounds__(256) void conv1_mfma_kernel(
    const _Float16* __restrict__ pre, const _Float16* __restrict__ frag1,
    signed char* __restrict__ out) {
  int tid = threadIdx.x;
  int wi = tid >> 6;
  int l = tid & 63;
  int lo = l & 31;
  int hi = l >> 5;
  int b = blockIdx.z;
  int h0 = blockIdx.y * 2;
  int wbase = blockIdx.x * 128 + wi * 32;
  int w = wbase + lo;

  const f16x8* fp = (const f16x8*)frag1;
  f16x8 bf[6];
#pragma unroll
  for (int s = 0; s < 6; ++s) bf[s] = fp[s * 64 + l];

  f32x16 acc0 = {}, acc1 = {};

  __builtin_amdgcn_s_setprio(1);
#pragma unroll
  for (int r = 0; r < 4; ++r) {  // input rows h0-1 .. h0+2 -> padded h0+r
    const _Float16* rp = pre + ((size_t)b * PP + (size_t)(h0 + r) * PC) * 8;
#pragma unroll
    for (int p = 0; p < 2; ++p) {
      int col = w + p * 2 + hi;  // padded col of x = w+2p+hi-1
      f16x8 av = {};
      if (!(p == 1 && hi == 1))  // k-slot pad only (not spatial)
        av = *(const f16x8*)(rp + (size_t)col * 8);
      if (r < 3) acc0 = __builtin_amdgcn_mfma_f32_32x32x16_f16(bf[r * 2 + p], av, acc0, 0, 0, 0);
      if (r > 0) acc1 = __builtin_amdgcn_mfma_f32_32x32x16_f16(bf[(r - 1) * 2 + p], av, acc1, 0, 0, 0);
    }
  }
  __builtin_amdgcn_s_setprio(0);

#pragma unroll
  for (int rr = 0; rr < 2; ++rr) {
    const f32x16& acc = rr ? acc1 : acc0;
    int q[16];
#pragma unroll
    for (int r = 0; r < 16; ++r) {
      int t = (int)rintf(acc[r] * 128.0f);
      q[r] = min(127, max(-127, t));
    }
    int v0 = pack4(q[0], q[1], q[2], q[3]);
    int v1 = pack4(q[4], q[5], q[6], q[7]);
    int v2 = pack4(q[8], q[9], q[10], q[11]);
    int v3 = pack4(q[12], q[13], q[14], q[15]);
    i32x4 ch = half_swap(v0, v1, v2, v3, hi);
    *(i32x4*)(out + ((size_t)b * PP + (size_t)(h0 + rr + 1) * PC + (w + 1)) * 32 + hi * 16) = ch;
  }
}

// ================= fused mid pairs: ring interleave + early bwB + setprio =
// 8 layer-B rows/block; 10 A-rows via 6-slot LDS ring. Iter k: A-pair k ->
// slots (2k)%6,(2k+1)%6; bwB(k-1) loads ISSUED BEFORE the barrier (their L2
// latency hides under barrier wait); ONE barrier; B-pair k-1 from ring.
// setprio(1) wraps both MFMA clusters (phase diversity across the 2
// resident blocks/CU). Slot disjointness unchanged (proven round 25).
template <int MODE>
__global__ __launch_bounds__(512, 4) void conv_fused_kernel(
    const signed char* __restrict__ in, const signed char* __restrict__ fragA,
    const signed char* __restrict__ fragB, signed char* __restrict__ out,
    int* __restrict__ gmax) {
  __shared__ int Aring[6 * 2 * PC * 4];  // 49536 B
  __shared__ int red[8][32];

  int tid = threadIdx.x;
  int wi = tid >> 6;
  int l = tid & 63;
  int lo = l & 31;
  int hi = l >> 5;
  int b = blockIdx.y;
  int hs = blockIdx.x * 8;  // layer-B output rows hs..hs+7
  int w = wi * 32 + lo;

  // zero ring col halo (cols 0 and 257 of each of 12 subrows)
  if (tid < 24) {
    int rr = tid >> 2, half = (tid >> 1) & 1, cs = tid & 1;
    i32x4 z = {};
    *(i32x4*)&Aring[((rr * 2 + half) * PC + (cs ? 257 : 0)) * 4] = z;
  }

  const i32x4* fpA = (const i32x4*)fragA;
  i32x4 bwA[9];
#pragma unroll
  for (int t = 0; t < 9; ++t) bwA[t] = fpA[t * 64 + l];

  int lanep = (w << 5) + (hi << 4);

  auto rowptr = [&](int ar) -> const signed char* {
    int prow = min(max(ar + 1, 0), 257);  // clamps land in zero halo
    return in + ((size_t)b * PP + (size_t)prow * PC) * 32 + lanep;
  };

  auto ring_store = [&](const i32x16& acc, int slot, bool valid) {
    int v0 = pack4(quant1(acc[0]), quant1(acc[1]), quant1(acc[2]), quant1(acc[3]));
    int v1 = pack4(quant1(acc[4]), quant1(acc[5]), quant1(acc[6]), quant1(acc[7]));
    int v2 = pack4(quant1(acc[8]), quant1(acc[9]), quant1(acc[10]), quant1(acc[11]));
    int v3 = pack4(quant1(acc[12]), quant1(acc[13]), quant1(acc[14]), quant1(acc[15]));
    i32x4 ch = half_swap(v0, v1, v2, v3, hi);
    if (!valid) ch = i32x4{};
    *(i32x4*)&Aring[((slot * 2 + hi) * PC + (w + 1)) * 4] = ch;
  };

  int mymax = -128;

#pragma unroll 1
  for (int k = 0; k < 5; ++k) {
    // ---- A-pair k: rows ar0, ar0+1 ----
    int ar0 = hs - 1 + 2 * k;
    i32x4 rin[4][3];
#pragma unroll
    for (int rr = 0; rr < 4; ++rr) {
      const signed char* rp = rowptr(ar0 - 1 + rr);
#pragma unroll
      for (int dx = 0; dx < 3; ++dx) rin[rr][dx] = *(const i32x4*)(rp + dx * 32);
    }
    i32x16 acc0 = {}, acc1 = {};
    __builtin_amdgcn_s_setprio(1);
#pragma unroll
    for (int t = 0; t < 9; ++t) {
      int dy = t / 3, dx = t % 3;
      acc0 = __builtin_amdgcn_mfma_i32_32x32x32_i8(bwA[t], rin[dy][dx], acc0, 0, 0, 0);
      acc1 = __builtin_amdgcn_mfma_i32_32x32x32_i8(bwA[t], rin[dy + 1][dx], acc1, 0, 0, 0);
    }
    __builtin_amdgcn_s_setprio(0);
    ring_store(acc0, (2 * k) % 6, (unsigned)ar0 < 256u);
    ring_store(acc1, (2 * k + 1) % 6, (unsigned)(ar0 + 1) < 256u);

    // ---- B-weights for pair k-1: issue BEFORE the barrier (no dependency;
    // L2 latency hides under the barrier wait). pz launder keeps the loads
    // per-iteration (hoisting them whole-loop would blow the VGPR cap).
    i32x4 bwB[9];
    if (k >= 1) {
      int pz = 0;
      asm volatile("" : "+v"(pz));
      const i32x4* fpB = (const i32x4*)fragB;
#pragma unroll
      for (int t = 0; t < 9; ++t) bwB[t] = fpB[t * 64 + l + pz];
    }

    __syncthreads();

    // ---- B-pair k-1: rows hs+2(k-1), +1 ----
    if (k >= 1) {
      int j = k - 1;
      i32x4 tp[4][3];
#pragma unroll
      for (int rr = 0; rr < 4; ++rr) {
        int slot = (2 * j + rr) % 6;  // A-row hs+2j-1+rr
#pragma unroll
        for (int dx = 0; dx < 3; ++dx)
          tp[rr][dx] = *(const i32x4*)&Aring[((slot * 2 + hi) * PC + (w + dx)) * 4];
      }
      i32x16 c0 = {}, c1 = {};
      __builtin_amdgcn_s_setprio(1);
#pragma unroll
      for (int t = 0; t < 9; ++t) {
        int dy = t / 3, dx = t % 3;
        if (MODE == 1) {
          c0 = __builtin_amdgcn_mfma_i32_32x32x32_i8(tp[dy][dx], bwB[t], c0, 0, 0, 0);
          c1 = __builtin_amdgcn_mfma_i32_32x32x32_i8(tp[dy + 1][dx], bwB[t], c1, 0, 0, 0);
        } else {
          c0 = __builtin_amdgcn_mfma_i32_32x32x32_i8(bwB[t], tp[dy][dx], c0, 0, 0, 0);
          c1 = __builtin_amdgcn_mfma_i32_32x32x32_i8(bwB[t], tp[dy + 1][dx], c1, 0, 0, 0);
        }
      }
      __builtin_amdgcn_s_setprio(0);
      if (MODE == 0) {
#pragma unroll
        for (int rr = 0; rr < 2; ++rr) {
          const i32x16& acc = rr ? c1 : c0;
          int v0 = pack4(quant1(acc[0]), quant1(acc[1]), quant1(acc[2]), quant1(acc[3]));
          int v1 = pack4(quant1(acc[4]), quant1(acc[5]), quant1(acc[6]), quant1(acc[7]));
          int v2 = pack4(quant1(acc[8]), quant1(acc[9]), quant1(acc[10]), quant1(acc[11]));
          int v3 = pack4(quant1(acc[12]), quant1(acc[13]), quant1(acc[14]), quant1(acc[15]));
          i32x4 ch = half_swap(v0, v1, v2, v3, hi);
          *(i32x4*)(out + ((size_t)b * PP + (size_t)(hs + 2 * j + rr + 1) * PC + (w + 1)) * 32 + hi * 16) = ch;
        }
      } else {
        mymax = quant_max(c1, quant_max(c0, mymax));
      }
    }
  }

  if (MODE == 1) {
    mymax = max(mymax, __shfl_xor(mymax, 32));
    if (hi == 0) red[wi][lo] = mymax;
    __syncthreads();
    if (tid < 32) {
      int m = -128;
#pragma unroll
      for (int r = 0; r < 8; ++r) m = max(m, red[r][tid]);
      atomicMax(&gmax[b * 32 + tid], m);
    }
  }
}

// ================= final FC =================
__global__ void fc_kernel(const int* __restrict__ gmax, const int* __restrict__ wfcq,
                          float* __restrict__ out) {
  int b = threadIdx.x;
  if (b < BB) {
    int acc = 0;
#pragma unroll
    for (int c = 0; c < 32; ++c) acc += gmax[b * 32 + c] * wfcq[c];
    int q = (acc + 63 + ((acc >> 7) & 1)) >> 7;  // rne(acc/128), exact
    q = min(127, max(-127, q));
    out[b] = (float)q * 0.0078125f;
  }
}

extern "C" void kernel_launch(void* const* d_in, const int* in_sizes, int n_in,
                              void* d_out, int out_size, void* d_ws, size_t ws_size,
                              hipStream_t stream) {
  const float* x   = (const float*)d_in[0];
  const float* w1  = (const float*)d_in[1];
  const float* wfc = (const float*)d_in[8];

  char* ws = (char*)d_ws;
  const size_t ACTP = (size_t)BB * PP * 32;  // 34,080,768 B padded act buffer
  signed char* A0    = (signed char*)ws;
  signed char* A1    = (signed char*)(ws + ACTP);
  _Float16*    pre   = (_Float16*)A1;  // dead before F0 writes A1
  _Float16*    frag1 = (_Float16*)(ws + 2 * ACTP);                 // 6144 B
  signed char* wfr   = (signed char*)(ws + 2 * ACTP + 6144);       // 6 x 9216
  int*         wfcq  = (int*)(ws + 2 * ACTP + 6144 + 6 * 9216);
  int*         gmax  = (int*)(ws + 2 * ACTP + 6144 + 6 * 9216 + 128);

  prep_kernel<<<4378, 256, 0, stream>>>(
      x, w1, (const float*)d_in[2], (const float*)d_in[3], (const float*)d_in[4],
      (const float*)d_in[5], (const float*)d_in[6], (const float*)d_in[7],
      wfc, pre, frag1, wfr, wfcq, gmax, A0);

  dim3 gridc1(2, 128, 16);  // conv1: 2-row pairs
  conv1_mfma_kernel<<<gridc1, 256, 0, stream>>>(pre, frag1, A0);
  pad_kernel<<<65, 256, 0, stream>>>(A1);  // A1 pads (after pre consumed)

  dim3 gf(32, 16);  // fused pairs: 8-row chunks, full width, 2 blocks/CU
  conv_fused_kernel<0><<<gf, 512, 0, stream>>>(A0, wfr + 0 * 9216, wfr + 1 * 9216, A1, nullptr);
  conv_fused_kernel<0><<<gf, 512, 0, stream>>>(A1, wfr + 2 * 9216, wfr + 3 * 9216, A0, nullptr);
  conv_fused_kernel<1><<<gf, 512, 0, stream>>>(A0, wfr + 4 * 9216, wfr + 5 * 9216, nullptr, gmax);
  fc_kernel<<<1, 64, 0, stream>>>(gmax, wfcq, (float*)d_out);
}

// Round 27
// 184.827 us; speedup vs baseline: 1.1634x; 1.1634x over previous
//
#include <hip/hip_runtime.h>

#define BB 16
#define HH 256
#define WW 256
#define PC 258                 // padded cols/rows
#define PP ((size_t)(PC * PC)) // 66564 px per padded img

typedef int i32x4 __attribute__((ext_vector_type(4)));
typedef int i32x16 __attribute__((ext_vector_type(16)));
typedef float f32x16 __attribute__((ext_vector_type(16)));
typedef _Float16 f16x8 __attribute__((ext_vector_type(8)));

// ================= fused prep =================
__global__ __launch_bounds__(256) void prep_kernel(
    const float* __restrict__ x, const float* __restrict__ w1,
    const float* __restrict__ w2, const float* __restrict__ w3,
    const float* __restrict__ w4, const float* __restrict__ w5,
    const float* __restrict__ w6, const float* __restrict__ w7,
    const float* __restrict__ wfc,
    _Float16* __restrict__ pre, _Float16* __restrict__ frag1,
    signed char* __restrict__ wfr, int* __restrict__ wfcq,
    int* __restrict__ gmax, signed char* __restrict__ A0) {
  int bid = blockIdx.x, tid = threadIdx.x;
  if (bid < 4096) {
    int px = bid * 256 + tid;  // 1,048,576 interior pixels
    int b = px >> 16, rem = px & 65535;
    int y = rem >> 8, xc = rem & 255;
    const float* xp = x + (size_t)b * 4 * 65536 + rem;
    f16x8 o;
#pragma unroll
    for (int ic = 0; ic < 4; ++ic) {
      float v = xp[ic * 65536];
      _Float16 hf = (_Float16)v;
      float r = v - (float)hf;
      o[ic * 2] = hf;
      o[ic * 2 + 1] = (_Float16)r;
    }
    *(f16x8*)(pre + ((size_t)b * PP + (size_t)(y + 1) * PC + (xc + 1)) * 8) = o;
  } else if (bid < 4312) {
    int i = (bid - 4096) * 256 + tid;  // 6 x 9216
    int layer = i / 9216, within = i - layer * 9216;
    const float* w = layer == 0 ? w2 : layer == 1 ? w3 : layer == 2 ? w4
                   : layer == 3 ? w5 : layer == 4 ? w6 : w7;
    int t = within >> 10;
    int l = (within >> 4) & 63;
    int j = within & 15;
    int ic = (l >> 5) * 16 + j;
    int oc = l & 31;
    int q = (int)rintf(w[oc * 288 + ic * 9 + t] * 128.0f);
    q = min(127, max(-127, q));
    wfr[(size_t)layer * 9216 + within] = (signed char)q;
  } else if (bid == 4312) {
    for (int p = tid; p < 384; p += 256) {
      int s = p >> 6, l = p & 63;
      int dr = s >> 1, pp = s & 1;
      int oc = l & 31, half = l >> 5;
      int dx = pp * 2 + half;
#pragma unroll
      for (int j = 0; j < 8; ++j) {
        int ic = j >> 1;
        _Float16 v = (_Float16)0.f;
        if (!(pp == 1 && half == 1)) {
          int q = (int)rintf(w1[oc * 36 + ic * 9 + dr * 3 + dx] * 128.0f);
          q = min(127, max(-127, q));
          v = (_Float16)((float)q * 0.0078125f);  // exact in fp16
        }
        frag1[s * 512 + l * 8 + j] = v;
      }
    }
    if (tid < 32) {
      int q = (int)rintf(wfc[tid] * 128.0f);
      q = min(127, max(-127, q));
      wfcq[tid] = q;
    }
    for (int i2 = tid; i2 < 512; i2 += 256) gmax[i2] = -128;
  } else {
    int idx = (bid - 4313) * 256 + tid;  // 16*1028 = 16448 pad px
    if (idx < 16448) {
      int img = idx / 1028, p = idx - img * 1028;
      int row, col;
      if (p < 258) { row = 0; col = p; }
      else if (p < 516) { row = 257; col = p - 258; }
      else { int q2 = p - 516; row = 1 + (q2 & 255); col = (q2 >> 8) ? 257 : 0; }
      size_t off = (size_t)img * PP + (size_t)row * PC + col;
      f16x8 z16 = {};
      *(f16x8*)(pre + off * 8) = z16;
      i32x4 z = {};
      ((i32x4*)(A0 + off * 32))[0] = z;
      ((i32x4*)(A0 + off * 32 + 16))[0] = z;
    }
  }
}

// zero the pads of A1 (must run AFTER conv1 consumed pre, which aliases A1)
__global__ __launch_bounds__(256) void pad_kernel(signed char* __restrict__ A1) {
  int idx = blockIdx.x * 256 + threadIdx.x;
  if (idx < 16448) {
    int img = idx / 1028, p = idx - img * 1028;
    int row, col;
    if (p < 258) { row = 0; col = p; }
    else if (p < 516) { row = 257; col = p - 258; }
    else { int q2 = p - 516; row = 1 + (q2 & 255); col = (q2 >> 8) ? 257 : 0; }
    size_t off = (size_t)img * PP + (size_t)row * PC + col;
    i32x4 z = {};
    ((i32x4*)(A1 + off * 32))[0] = z;
    ((i32x4*)(A1 + off * 32 + 16))[0] = z;
  }
}

__device__ __forceinline__ int pack4(int q0, int q1, int q2, int q3) {
  return (q0 & 255) | ((q1 & 255) << 8) | ((q2 & 255) << 16) | ((q3 & 255) << 24);
}

// Exact integer RNE: rne(a/128) = (a + 63 + ((a>>7)&1)) >> 7, bit-identical.
__device__ __forceinline__ int quant1(int a) {
  int q = (a + 63 + ((a >> 7) & 1)) >> 7;
  return min(127, max(-127, q));
}

__device__ __forceinline__ int quant_max(const i32x16& acc, int mymax) {
#pragma unroll
  for (int r = 0; r < 16; ++r) mymax = max(mymax, quant1(acc[r]));
  return mymax;
}

__device__ __forceinline__ i32x4 half_swap(int v0, int v1, int v2, int v3, int hi) {
  int s0 = hi ? v0 : v2;
  int s1 = hi ? v1 : v3;
  int r0 = __shfl_xor(s0, 32);
  int r1 = __shfl_xor(s1, 32);
  i32x4 ch;
  ch.x = hi ? r0 : v0;
  ch.y = hi ? v2 : r0;
  ch.z = hi ? r1 : v1;
  ch.w = hi ? v3 : r1;
  return ch;
}

// ================= conv1: padded pre -> padded A0 ======
__global__ __launch_bounds__(256) void conv1_mfma_kernel(
    const _Float16* __restrict__ pre, const _Float16* __restrict__ frag1,
    signed char* __restrict__ out) {
  int tid = threadIdx.x;
  int wi = tid >> 6;
  int l = tid & 63;
  int lo = l & 31;
  int hi = l >> 5;
  int b = blockIdx.z;
  int h0 = blockIdx.y * 2;
  int wbase = blockIdx.x * 128 + wi * 32;
  int w = wbase + lo;

  const f16x8* fp = (const f16x8*)frag1;
  f16x8 bf[6];
#pragma unroll
  for (int s = 0; s < 6; ++s) bf[s] = fp[s * 64 + l];

  f32x16 acc0 = {}, acc1 = {};

  __builtin_amdgcn_s_setprio(1);
#pragma unroll
  for (int r = 0; r < 4; ++r) {  // input rows h0-1 .. h0+2 -> padded h0+r
    const _Float16* rp = pre + ((size_t)b * PP + (size_t)(h0 + r) * PC) * 8;
#pragma unroll
    for (int p = 0; p < 2; ++p) {
      int col = w + p * 2 + hi;  // padded col of x = w+2p+hi-1
      f16x8 av = {};
      if (!(p == 1 && hi == 1))  // k-slot pad only (not spatial)
        av = *(const f16x8*)(rp + (size_t)col * 8);
      if (r < 3) acc0 = __builtin_amdgcn_mfma_f32_32x32x16_f16(bf[r * 2 + p], av, acc0, 0, 0, 0);
      if (r > 0) acc1 = __builtin_amdgcn_mfma_f32_32x32x16_f16(bf[(r - 1) * 2 + p], av, acc1, 0, 0, 0);
    }
  }
  __builtin_amdgcn_s_setprio(0);

#pragma unroll
  for (int rr = 0; rr < 2; ++rr) {
    const f32x16& acc = rr ? acc1 : acc0;
    int q[16];
#pragma unroll
    for (int r = 0; r < 16; ++r) {
      int t = (int)rintf(acc[r] * 128.0f);
      q[r] = min(127, max(-127, t));
    }
    int v0 = pack4(q[0], q[1], q[2], q[3]);
    int v1 = pack4(q[4], q[5], q[6], q[7]);
    int v2 = pack4(q[8], q[9], q[10], q[11]);
    int v3 = pack4(q[12], q[13], q[14], q[15]);
    i32x4 ch = half_swap(v0, v1, v2, v3, hi);
    *(i32x4*)(out + ((size_t)b * PP + (size_t)(h0 + rr + 1) * PC + (w + 1)) * 32 + hi * 16) = ch;
  }
}

// ================= fused mid pairs: ring interleave (round-25 form) =======
// 8 layer-B rows/block; 10 A-rows via 6-slot LDS ring. Iter k: A-pair k ->
// slots (2k)%6,(2k+1)%6; ONE barrier; B-pair k-1 from ring (bwB loaded AFTER
// the barrier — keeping it live across the barrier spilled in round 26:
// FETCH/WRITE 33->110/150 MB). setprio wraps MFMA clusters only (SALU, free).
template <int MODE>
__global__ __launch_bounds__(512, 4) void conv_fused_kernel(
    const signed char* __restrict__ in, const signed char* __restrict__ fragA,
    const signed char* __restrict__ fragB, signed char* __restrict__ out,
    int* __restrict__ gmax) {
  __shared__ int Aring[6 * 2 * PC * 4];  // 49536 B
  __shared__ int red[8][32];

  int tid = threadIdx.x;
  int wi = tid >> 6;
  int l = tid & 63;
  int lo = l & 31;
  int hi = l >> 5;
  int b = blockIdx.y;
  int hs = blockIdx.x * 8;  // layer-B output rows hs..hs+7
  int w = wi * 32 + lo;

  // zero ring col halo (cols 0 and 257 of each of 12 subrows)
  if (tid < 24) {
    int rr = tid >> 2, half = (tid >> 1) & 1, cs = tid & 1;
    i32x4 z = {};
    *(i32x4*)&Aring[((rr * 2 + half) * PC + (cs ? 257 : 0)) * 4] = z;
  }

  const i32x4* fpA = (const i32x4*)fragA;
  i32x4 bwA[9];
#pragma unroll
  for (int t = 0; t < 9; ++t) bwA[t] = fpA[t * 64 + l];

  int lanep = (w << 5) + (hi << 4);

  auto rowptr = [&](int ar) -> const signed char* {
    int prow = min(max(ar + 1, 0), 257);  // clamps land in zero halo
    return in + ((size_t)b * PP + (size_t)prow * PC) * 32 + lanep;
  };

  auto ring_store = [&](const i32x16& acc, int slot, bool valid) {
    int v0 = pack4(quant1(acc[0]), quant1(acc[1]), quant1(acc[2]), quant1(acc[3]));
    int v1 = pack4(quant1(acc[4]), quant1(acc[5]), quant1(acc[6]), quant1(acc[7]));
    int v2 = pack4(quant1(acc[8]), quant1(acc[9]), quant1(acc[10]), quant1(acc[11]));
    int v3 = pack4(quant1(acc[12]), quant1(acc[13]), quant1(acc[14]), quant1(acc[15]));
    i32x4 ch = half_swap(v0, v1, v2, v3, hi);
    if (!valid) ch = i32x4{};
    *(i32x4*)&Aring[((slot * 2 + hi) * PC + (w + 1)) * 4] = ch;
  };

  int mymax = -128;

#pragma unroll 1
  for (int k = 0; k < 5; ++k) {
    // ---- A-pair k: rows ar0, ar0+1 ----
    int ar0 = hs - 1 + 2 * k;
    i32x4 rin[4][3];
#pragma unroll
    for (int rr = 0; rr < 4; ++rr) {
      const signed char* rp = rowptr(ar0 - 1 + rr);
#pragma unroll
      for (int dx = 0; dx < 3; ++dx) rin[rr][dx] = *(const i32x4*)(rp + dx * 32);
    }
    i32x16 acc0 = {}, acc1 = {};
    __builtin_amdgcn_s_setprio(1);
#pragma unroll
    for (int t = 0; t < 9; ++t) {
      int dy = t / 3, dx = t % 3;
      acc0 = __builtin_amdgcn_mfma_i32_32x32x32_i8(bwA[t], rin[dy][dx], acc0, 0, 0, 0);
      acc1 = __builtin_amdgcn_mfma_i32_32x32x32_i8(bwA[t], rin[dy + 1][dx], acc1, 0, 0, 0);
    }
    __builtin_amdgcn_s_setprio(0);
    ring_store(acc0, (2 * k) % 6, (unsigned)ar0 < 256u);
    ring_store(acc1, (2 * k + 1) % 6, (unsigned)(ar0 + 1) < 256u);

    __syncthreads();

    // ---- B-pair k-1: rows hs+2(k-1), +1 ----
    if (k >= 1) {
      int j = k - 1;
      int pz = 0;
      asm volatile("" : "+v"(pz));  // keep bwB loads inside the loop
      const i32x4* fpB = (const i32x4*)fragB;
      i32x4 bwB[9];
#pragma unroll
      for (int t = 0; t < 9; ++t) bwB[t] = fpB[t * 64 + l + pz];

      i32x4 tp[4][3];
#pragma unroll
      for (int rr = 0; rr < 4; ++rr) {
        int slot = (2 * j + rr) % 6;  // A-row hs+2j-1+rr
#pragma unroll
        for (int dx = 0; dx < 3; ++dx)
          tp[rr][dx] = *(const i32x4*)&Aring[((slot * 2 + hi) * PC + (w + dx)) * 4];
      }
      i32x16 c0 = {}, c1 = {};
      __builtin_amdgcn_s_setprio(1);
#pragma unroll
      for (int t = 0; t < 9; ++t) {
        int dy = t / 3, dx = t % 3;
        if (MODE == 1) {
          c0 = __builtin_amdgcn_mfma_i32_32x32x32_i8(tp[dy][dx], bwB[t], c0, 0, 0, 0);
          c1 = __builtin_amdgcn_mfma_i32_32x32x32_i8(tp[dy + 1][dx], bwB[t], c1, 0, 0, 0);
        } else {
          c0 = __builtin_amdgcn_mfma_i32_32x32x32_i8(bwB[t], tp[dy][dx], c0, 0, 0, 0);
          c1 = __builtin_amdgcn_mfma_i32_32x32x32_i8(bwB[t], tp[dy + 1][dx], c1, 0, 0, 0);
        }
      }
      __builtin_amdgcn_s_setprio(0);
      if (MODE == 0) {
#pragma unroll
        for (int rr = 0; rr < 2; ++rr) {
          const i32x16& acc = rr ? c1 : c0;
          int v0 = pack4(quant1(acc[0]), quant1(acc[1]), quant1(acc[2]), quant1(acc[3]));
          int v1 = pack4(quant1(acc[4]), quant1(acc[5]), quant1(acc[6]), quant1(acc[7]));
          int v2 = pack4(quant1(acc[8]), quant1(acc[9]), quant1(acc[10]), quant1(acc[11]));
          int v3 = pack4(quant1(acc[12]), quant1(acc[13]), quant1(acc[14]), quant1(acc[15]));
          i32x4 ch = half_swap(v0, v1, v2, v3, hi);
          *(i32x4*)(out + ((size_t)b * PP + (size_t)(hs + 2 * j + rr + 1) * PC + (w + 1)) * 32 + hi * 16) = ch;
        }
      } else {
        mymax = quant_max(c1, quant_max(c0, mymax));
      }
    }
  }

  if (MODE == 1) {
    mymax = max(mymax, __shfl_xor(mymax, 32));
    if (hi == 0) red[wi][lo] = mymax;
    __syncthreads();
    if (tid < 32) {
      int m = -128;
#pragma unroll
      for (int r = 0; r < 8; ++r) m = max(m, red[r][tid]);
      atomicMax(&gmax[b * 32 + tid], m);
    }
  }
}

// ================= final FC =================
__global__ void fc_kernel(const int* __restrict__ gmax, const int* __restrict__ wfcq,
                          float* __restrict__ out) {
  int b = threadIdx.x;
  if (b < BB) {
    int acc = 0;
#pragma unroll
    for (int c = 0; c < 32; ++c) acc += gmax[b * 32 + c] * wfcq[c];
    int q = (acc + 63 + ((acc >> 7) & 1)) >> 7;  // rne(acc/128), exact
    q = min(127, max(-127, q));
    out[b] = (float)q * 0.0078125f;
  }
}

extern "C" void kernel_launch(void* const* d_in, const int* in_sizes, int n_in,
                              void* d_out, int out_size, void* d_ws, size_t ws_size,
                              hipStream_t stream) {
  const float* x   = (const float*)d_in[0];
  const float* w1  = (const float*)d_in[1];
  const float* wfc = (const float*)d_in[8];

  char* ws = (char*)d_ws;
  const size_t ACTP = (size_t)BB * PP * 32;  // 34,080,768 B padded act buffer
  signed char* A0    = (signed char*)ws;
  signed char* A1    = (signed char*)(ws + ACTP);
  _Float16*    pre   = (_Float16*)A1;  // dead before F0 writes A1
  _Float16*    frag1 = (_Float16*)(ws + 2 * ACTP);                 // 6144 B
  signed char* wfr   = (signed char*)(ws + 2 * ACTP + 6144);       // 6 x 9216
  int*         wfcq  = (int*)(ws + 2 * ACTP + 6144 + 6 * 9216);
  int*         gmax  = (int*)(ws + 2 * ACTP + 6144 + 6 * 9216 + 128);

  prep_kernel<<<4378, 256, 0, stream>>>(
      x, w1, (const float*)d_in[2], (const float*)d_in[3], (const float*)d_in[4],
      (const float*)d_in[5], (const float*)d_in[6], (const float*)d_in[7],
      wfc, pre, frag1, wfr, wfcq, gmax, A0);

  dim3 gridc1(2, 128, 16);  // conv1: 2-row pairs
  conv1_mfma_kernel<<<gridc1, 256, 0, stream>>>(pre, frag1, A0);
  pad_kernel<<<65, 256, 0, stream>>>(A1);  // A1 pads (after pre consumed)

  dim3 gf(32, 16);  // fused pairs: 8-row chunks, full width, 2 blocks/CU
  conv_fused_kernel<0><<<gf, 512, 0, stream>>>(A0, wfr + 0 * 9216, wfr + 1 * 9216, A1, nullptr);
  conv_fused_kernel<0><<<gf, 512, 0, stream>>>(A1, wfr + 2 * 9216, wfr + 3 * 9216, A0, nullptr);
  conv_fused_kernel<1><<<gf, 512, 0, stream>>>(A0, wfr + 4 * 9216, wfr + 5 * 9216, nullptr, gmax);
  fc_kernel<<<1, 64, 0, stream>>>(gmax, wfcq, (float*)d_out);
}

// Round 28
// 132.758 us; speedup vs baseline: 1.6198x; 1.3922x over previous
//
#include <hip/hip_runtime.h>

#define BB 16
#define HH 256
#define WW 256
#define PC 258                 // padded cols/rows
#define PP ((size_t)(PC * PC)) // 66564 px per padded img

typedef int i32x4 __attribute__((ext_vector_type(4)));
typedef int i32x16 __attribute__((ext_vector_type(16)));
typedef float f32x16 __attribute__((ext_vector_type(16)));
typedef _Float16 f16x8 __attribute__((ext_vector_type(8)));

// ================= fused prep =================
__global__ __launch_bounds__(256) void prep_kernel(
    const float* __restrict__ x, const float* __restrict__ w1,
    const float* __restrict__ w2, const float* __restrict__ w3,
    const float* __restrict__ w4, const float* __restrict__ w5,
    const float* __restrict__ w6, const float* __restrict__ w7,
    const float* __restrict__ wfc,
    _Float16* __restrict__ pre, _Float16* __restrict__ frag1,
    signed char* __restrict__ wfr, int* __restrict__ wfcq,
    int* __restrict__ gmax, signed char* __restrict__ A0) {
  int bid = blockIdx.x, tid = threadIdx.x;
  if (bid < 4096) {
    int px = bid * 256 + tid;  // 1,048,576 interior pixels
    int b = px >> 16, rem = px & 65535;
    int y = rem >> 8, xc = rem & 255;
    const float* xp = x + (size_t)b * 4 * 65536 + rem;
    f16x8 o;
#pragma unroll
    for (int ic = 0; ic < 4; ++ic) {
      float v = xp[ic * 65536];
      _Float16 hf = (_Float16)v;
      float r = v - (float)hf;
      o[ic * 2] = hf;
      o[ic * 2 + 1] = (_Float16)r;
    }
    *(f16x8*)(pre + ((size_t)b * PP + (size_t)(y + 1) * PC + (xc + 1)) * 8) = o;
  } else if (bid < 4312) {
    int i = (bid - 4096) * 256 + tid;  // 6 x 9216
    int layer = i / 9216, within = i - layer * 9216;
    const float* w = layer == 0 ? w2 : layer == 1 ? w3 : layer == 2 ? w4
                   : layer == 3 ? w5 : layer == 4 ? w6 : w7;
    int t = within >> 10;
    int l = (within >> 4) & 63;
    int j = within & 15;
    int ic = (l >> 5) * 16 + j;
    int oc = l & 31;
    int q = (int)rintf(w[oc * 288 + ic * 9 + t] * 128.0f);
    q = min(127, max(-127, q));
    wfr[(size_t)layer * 9216 + within] = (signed char)q;
  } else if (bid == 4312) {
    for (int p = tid; p < 384; p += 256) {
      int s = p >> 6, l = p & 63;
      int dr = s >> 1, pp = s & 1;
      int oc = l & 31, half = l >> 5;
      int dx = pp * 2 + half;
#pragma unroll
      for (int j = 0; j < 8; ++j) {
        int ic = j >> 1;
        _Float16 v = (_Float16)0.f;
        if (!(pp == 1 && half == 1)) {
          int q = (int)rintf(w1[oc * 36 + ic * 9 + dr * 3 + dx] * 128.0f);
          q = min(127, max(-127, q));
          v = (_Float16)((float)q * 0.0078125f);  // exact in fp16
        }
        frag1[s * 512 + l * 8 + j] = v;
      }
    }
    if (tid < 32) {
      int q = (int)rintf(wfc[tid] * 128.0f);
      q = min(127, max(-127, q));
      wfcq[tid] = q;
    }
    for (int i2 = tid; i2 < 512; i2 += 256) gmax[i2] = -128;
  } else {
    int idx = (bid - 4313) * 256 + tid;  // 16*1028 = 16448 pad px
    if (idx < 16448) {
      int img = idx / 1028, p = idx - img * 1028;
      int row, col;
      if (p < 258) { row = 0; col = p; }
      else if (p < 516) { row = 257; col = p - 258; }
      else { int q2 = p - 516; row = 1 + (q2 & 255); col = (q2 >> 8) ? 257 : 0; }
      size_t off = (size_t)img * PP + (size_t)row * PC + col;
      f16x8 z16 = {};
      *(f16x8*)(pre + off * 8) = z16;
      i32x4 z = {};
      ((i32x4*)(A0 + off * 32))[0] = z;
      ((i32x4*)(A0 + off * 32 + 16))[0] = z;
    }
  }
}

// zero the pads of A1 (must run AFTER conv1 consumed pre, which aliases A1)
__global__ __launch_bounds__(256) void pad_kernel(signed char* __restrict__ A1) {
  int idx = blockIdx.x * 256 + threadIdx.x;
  if (idx < 16448) {
    int img = idx / 1028, p = idx - img * 1028;
    int row, col;
    if (p < 258) { row = 0; col = p; }
    else if (p < 516) { row = 257; col = p - 258; }
    else { int q2 = p - 516; row = 1 + (q2 & 255); col = (q2 >> 8) ? 257 : 0; }
    size_t off = (size_t)img * PP + (size_t)row * PC + col;
    i32x4 z = {};
    ((i32x4*)(A1 + off * 32))[0] = z;
    ((i32x4*)(A1 + off * 32 + 16))[0] = z;
  }
}

__device__ __forceinline__ int pack4(int q0, int q1, int q2, int q3) {
  return (q0 & 255) | ((q1 & 255) << 8) | ((q2 & 255) << 16) | ((q3 & 255) << 24);
}

// Exact integer RNE: rne(a/128) = (a + 63 + ((a>>7)&1)) >> 7, bit-identical.
__device__ __forceinline__ int quant1(int a) {
  int q = (a + 63 + ((a >> 7) & 1)) >> 7;
  return min(127, max(-127, q));
}

__device__ __forceinline__ int quant_max(const i32x16& acc, int mymax) {
#pragma unroll
  for (int r = 0; r < 16; ++r) mymax = max(mymax, quant1(acc[r]));
  return mymax;
}

__device__ __forceinline__ i32x4 half_swap(int v0, int v1, int v2, int v3, int hi) {
  int s0 = hi ? v0 : v2;
  int s1 = hi ? v1 : v3;
  int r0 = __shfl_xor(s0, 32);
  int r1 = __shfl_xor(s1, 32);
  i32x4 ch;
  ch.x = hi ? r0 : v0;
  ch.y = hi ? v2 : r0;
  ch.z = hi ? r1 : v1;
  ch.w = hi ? v3 : r1;
  return ch;
}

// ================= conv1: padded pre -> padded A0 ======
__global__ __launch_bounds__(256) void conv1_mfma_kernel(
    const _Float16* __restrict__ pre, const _Float16* __restrict__ frag1,
    signed char* __restrict__ out) {
  int tid = threadIdx.x;
  int wi = tid >> 6;
  int l = tid & 63;
  int lo = l & 31;
  int hi = l >> 5;
  int b = blockIdx.z;
  int h0 = blockIdx.y * 2;
  int wbase = blockIdx.x * 128 + wi * 32;
  int w = wbase + lo;

  const f16x8* fp = (const f16x8*)frag1;
  f16x8 bf[6];
#pragma unroll
  for (int s = 0; s < 6; ++s) bf[s] = fp[s * 64 + l];

  f32x16 acc0 = {}, acc1 = {};

#pragma unroll
  for (int r = 0; r < 4; ++r) {  // input rows h0-1 .. h0+2 -> padded h0+r
    const _Float16* rp = pre + ((size_t)b * PP + (size_t)(h0 + r) * PC) * 8;
#pragma unroll
    for (int p = 0; p < 2; ++p) {
      int col = w + p * 2 + hi;  // padded col of x = w+2p+hi-1
      f16x8 av = {};
      if (!(p == 1 && hi == 1))  // k-slot pad only (not spatial)
        av = *(const f16x8*)(rp + (size_t)col * 8);
      if (r < 3) acc0 = __builtin_amdgcn_mfma_f32_32x32x16_f16(bf[r * 2 + p], av, acc0, 0, 0, 0);
      if (r > 0) acc1 = __builtin_amdgcn_mfma_f32_32x32x16_f16(bf[(r - 1) * 2 + p], av, acc1, 0, 0, 0);
    }
  }

#pragma unroll
  for (int rr = 0; rr < 2; ++rr) {
    const f32x16& acc = rr ? acc1 : acc0;
    int q[16];
#pragma unroll
    for (int r = 0; r < 16; ++r) {
      int t = (int)rintf(acc[r] * 128.0f);
      q[r] = min(127, max(-127, t));
    }
    int v0 = pack4(q[0], q[1], q[2], q[3]);
    int v1 = pack4(q[4], q[5], q[6], q[7]);
    int v2 = pack4(q[8], q[9], q[10], q[11]);
    int v3 = pack4(q[12], q[13], q[14], q[15]);
    i32x4 ch = half_swap(v0, v1, v2, v3, hi);
    *(i32x4*)(out + ((size_t)b * PP + (size_t)(h0 + rr + 1) * PC + (w + 1)) * 32 + hi * 16) = ch;
  }
}

// ================= fused mid pairs: ring-buffer phase interleave ==========
// Round-25 form exactly (best measured: 133.05 us, no spill). No setprio
// (round 27: its scheduling fences extended live ranges -> scratch spills),
// bwB loaded AFTER the barrier (round 26: cross-barrier staging spilled).
template <int MODE>
__global__ __launch_bounds__(512, 4) void conv_fused_kernel(
    const signed char* __restrict__ in, const signed char* __restrict__ fragA,
    const signed char* __restrict__ fragB, signed char* __restrict__ out,
    int* __restrict__ gmax) {
  __shared__ int Aring[6 * 2 * PC * 4];  // 49536 B
  __shared__ int red[8][32];

  int tid = threadIdx.x;
  int wi = tid >> 6;
  int l = tid & 63;
  int lo = l & 31;
  int hi = l >> 5;
  int b = blockIdx.y;
  int hs = blockIdx.x * 8;  // layer-B output rows hs..hs+7
  int w = wi * 32 + lo;

  // zero ring col halo (cols 0 and 257 of each of 12 subrows)
  if (tid < 24) {
    int rr = tid >> 2, half = (tid >> 1) & 1, cs = tid & 1;
    i32x4 z = {};
    *(i32x4*)&Aring[((rr * 2 + half) * PC + (cs ? 257 : 0)) * 4] = z;
  }

  const i32x4* fpA = (const i32x4*)fragA;
  i32x4 bwA[9];
#pragma unroll
  for (int t = 0; t < 9; ++t) bwA[t] = fpA[t * 64 + l];

  int lanep = (w << 5) + (hi << 4);

  auto rowptr = [&](int ar) -> const signed char* {
    int prow = min(max(ar + 1, 0), 257);  // clamps land in zero halo
    return in + ((size_t)b * PP + (size_t)prow * PC) * 32 + lanep;
  };

  auto ring_store = [&](const i32x16& acc, int slot, bool valid) {
    int v0 = pack4(quant1(acc[0]), quant1(acc[1]), quant1(acc[2]), quant1(acc[3]));
    int v1 = pack4(quant1(acc[4]), quant1(acc[5]), quant1(acc[6]), quant1(acc[7]));
    int v2 = pack4(quant1(acc[8]), quant1(acc[9]), quant1(acc[10]), quant1(acc[11]));
    int v3 = pack4(quant1(acc[12]), quant1(acc[13]), quant1(acc[14]), quant1(acc[15]));
    i32x4 ch = half_swap(v0, v1, v2, v3, hi);
    if (!valid) ch = i32x4{};
    *(i32x4*)&Aring[((slot * 2 + hi) * PC + (w + 1)) * 4] = ch;
  };

  int mymax = -128;

#pragma unroll 1
  for (int k = 0; k < 5; ++k) {
    // ---- A-pair k: rows ar0, ar0+1 ----
    int ar0 = hs - 1 + 2 * k;
    i32x4 rin[4][3];
#pragma unroll
    for (int rr = 0; rr < 4; ++rr) {
      const signed char* rp = rowptr(ar0 - 1 + rr);
#pragma unroll
      for (int dx = 0; dx < 3; ++dx) rin[rr][dx] = *(const i32x4*)(rp + dx * 32);
    }
    i32x16 acc0 = {}, acc1 = {};
#pragma unroll
    for (int t = 0; t < 9; ++t) {
      int dy = t / 3, dx = t % 3;
      acc0 = __builtin_amdgcn_mfma_i32_32x32x32_i8(bwA[t], rin[dy][dx], acc0, 0, 0, 0);
      acc1 = __builtin_amdgcn_mfma_i32_32x32x32_i8(bwA[t], rin[dy + 1][dx], acc1, 0, 0, 0);
    }
    ring_store(acc0, (2 * k) % 6, (unsigned)ar0 < 256u);
    ring_store(acc1, (2 * k + 1) % 6, (unsigned)(ar0 + 1) < 256u);

    __syncthreads();

    // ---- B-pair k-1: rows hs+2(k-1), +1 ----
    if (k >= 1) {
      int j = k - 1;
      int pz = 0;
      asm volatile("" : "+v"(pz));  // keep bwB loads inside the loop
      const i32x4* fpB = (const i32x4*)fragB;
      i32x4 bwB[9];
#pragma unroll
      for (int t = 0; t < 9; ++t) bwB[t] = fpB[t * 64 + l + pz];

      i32x4 tp[4][3];
#pragma unroll
      for (int rr = 0; rr < 4; ++rr) {
        int slot = (2 * j + rr) % 6;  // A-row hs+2j-1+rr
#pragma unroll
        for (int dx = 0; dx < 3; ++dx)
          tp[rr][dx] = *(const i32x4*)&Aring[((slot * 2 + hi) * PC + (w + dx)) * 4];
      }
      i32x16 c0 = {}, c1 = {};
#pragma unroll
      for (int t = 0; t < 9; ++t) {
        int dy = t / 3, dx = t % 3;
        if (MODE == 1) {
          c0 = __builtin_amdgcn_mfma_i32_32x32x32_i8(tp[dy][dx], bwB[t], c0, 0, 0, 0);
          c1 = __builtin_amdgcn_mfma_i32_32x32x32_i8(tp[dy + 1][dx], bwB[t], c1, 0, 0, 0);
        } else {
          c0 = __builtin_amdgcn_mfma_i32_32x32x32_i8(bwB[t], tp[dy][dx], c0, 0, 0, 0);
          c1 = __builtin_amdgcn_mfma_i32_32x32x32_i8(bwB[t], tp[dy + 1][dx], c1, 0, 0, 0);
        }
      }
      if (MODE == 0) {
#pragma unroll
        for (int rr = 0; rr < 2; ++rr) {
          const i32x16& acc = rr ? c1 : c0;
          int v0 = pack4(quant1(acc[0]), quant1(acc[1]), quant1(acc[2]), quant1(acc[3]));
          int v1 = pack4(quant1(acc[4]), quant1(acc[5]), quant1(acc[6]), quant1(acc[7]));
          int v2 = pack4(quant1(acc[8]), quant1(acc[9]), quant1(acc[10]), quant1(acc[11]));
          int v3 = pack4(quant1(acc[12]), quant1(acc[13]), quant1(acc[14]), quant1(acc[15]));
          i32x4 ch = half_swap(v0, v1, v2, v3, hi);
          *(i32x4*)(out + ((size_t)b * PP + (size_t)(hs + 2 * j + rr + 1) * PC + (w + 1)) * 32 + hi * 16) = ch;
        }
      } else {
        mymax = quant_max(c1, quant_max(c0, mymax));
      }
    }
  }

  if (MODE == 1) {
    mymax = max(mymax, __shfl_xor(mymax, 32));
    if (hi == 0) red[wi][lo] = mymax;
    __syncthreads();
    if (tid < 32) {
      int m = -128;
#pragma unroll
      for (int r = 0; r < 8; ++r) m = max(m, red[r][tid]);
      atomicMax(&gmax[b * 32 + tid], m);
    }
  }
}

// ================= final FC =================
__global__ void fc_kernel(const int* __restrict__ gmax, const int* __restrict__ wfcq,
                          float* __restrict__ out) {
  int b = threadIdx.x;
  if (b < BB) {
    int acc = 0;
#pragma unroll
    for (int c = 0; c < 32; ++c) acc += gmax[b * 32 + c] * wfcq[c];
    int q = (acc + 63 + ((acc >> 7) & 1)) >> 7;  // rne(acc/128), exact
    q = min(127, max(-127, q));
    out[b] = (float)q * 0.0078125f;
  }
}

extern "C" void kernel_launch(void* const* d_in, const int* in_sizes, int n_in,
                              void* d_out, int out_size, void* d_ws, size_t ws_size,
                              hipStream_t stream) {
  const float* x   = (const float*)d_in[0];
  const float* w1  = (const float*)d_in[1];
  const float* wfc = (const float*)d_in[8];

  char* ws = (char*)d_ws;
  const size_t ACTP = (size_t)BB * PP * 32;  // 34,080,768 B padded act buffer
  signed char* A0    = (signed char*)ws;
  signed char* A1    = (signed char*)(ws + ACTP);
  _Float16*    pre   = (_Float16*)A1;  // dead before F0 writes A1
  _Float16*    frag1 = (_Float16*)(ws + 2 * ACTP);                 // 6144 B
  signed char* wfr   = (signed char*)(ws + 2 * ACTP + 6144);       // 6 x 9216
  int*         wfcq  = (int*)(ws + 2 * ACTP + 6144 + 6 * 9216);
  int*         gmax  = (int*)(ws + 2 * ACTP + 6144 + 6 * 9216 + 128);

  prep_kernel<<<4378, 256, 0, stream>>>(
      x, w1, (const float*)d_in[2], (const float*)d_in[3], (const float*)d_in[4],
      (const float*)d_in[5], (const float*)d_in[6], (const float*)d_in[7],
      wfc, pre, frag1, wfr, wfcq, gmax, A0);

  dim3 gridc1(2, 128, 16);  // conv1: 2-row pairs
  conv1_mfma_kernel<<<gridc1, 256, 0, stream>>>(pre, frag1, A0);
  pad_kernel<<<65, 256, 0, stream>>>(A1);  // A1 pads (after pre consumed)

  dim3 gf(32, 16);  // fused pairs: 8-row chunks, full width, 2 blocks/CU
  conv_fused_kernel<0><<<gf, 512, 0, stream>>>(A0, wfr + 0 * 9216, wfr + 1 * 9216, A1, nullptr);
  conv_fused_kernel<0><<<gf, 512, 0, stream>>>(A1, wfr + 2 * 9216, wfr + 3 * 9216, A0, nullptr);
  conv_fused_kernel<1><<<gf, 512, 0, stream>>>(A0, wfr + 4 * 9216, wfr + 5 * 9216, nullptr, gmax);
  fc_kernel<<<1, 64, 0, stream>>>(gmax, wfcq, (float*)d_out);
}